// Round 1
// baseline (82.987 us; speedup 1.0000x reference)
//
#include <hip/hip_runtime.h>

// dissected Conv2d == standard 3x3 conv, NCHW, pad=1, fp32 in/out, bf16 MFMA inside.
// B=8, C_in=C_out=64, H=W=56.

typedef __attribute__((ext_vector_type(8))) short bf8_t;   // 8 bf16 = 4 VGPR (MFMA A/B frag)
typedef __attribute__((ext_vector_type(4))) float f4_t;    // MFMA C/D frag

#define IC 64
#define OC 64
#define HH 56
#define WW 56
#define NB 8
#define ROWS 2                 // output rows per block
#define RB (HH / ROWS)         // 28 row-blocks
#define NPIX (ROWS * WW)       // 112 pixels per block
#define NT (NPIX / 16)         // 7 pixel tiles (N dim of MFMA)
#define LC (WW + 2)            // 58 cols in LDS tile (halo)
#define LR (ROWS + 2)          // 4 rows in LDS tile (halo)
#define NS ((IC * 9) / 32)     // 18 K-steps of K=32
#define WSTRIDE 578            // padded weight-LDS row stride (578*2B = 289 words, 289%32==1)

__device__ __forceinline__ unsigned short f2bf(float f) {
    // round-to-nearest-even fp32 -> bf16 (weights/x are finite, no NaN handling needed)
    unsigned u = __float_as_uint(f);
    return (unsigned short)((u + 0x7FFFu + ((u >> 16) & 1u)) >> 16);
}

__global__ __launch_bounds__(256)
void conv3x3_mfma(const float* __restrict__ x, const float* __restrict__ w,
                  const float* __restrict__ bias, float* __restrict__ out) {
    // One LDS buffer, two phases: weight bounce (73,984 B), then x tile (29,696 B).
    __shared__ unsigned short lds[OC * WSTRIDE];

    const int tid  = threadIdx.x;
    const int wv   = tid >> 6;        // wave 0..3 -> oc group
    const int lane = tid & 63;
    const int kg   = lane >> 4;       // k-group 0..3 within MFMA fragment
    const int l15  = lane & 15;

    const int bx = blockIdx.x;
    const int b  = bx / RB;
    const int h0 = (bx - b * RB) * ROWS;

    // ---- Phase 1: coalesced fill of weight LDS (fp32 -> bf16, padded stride) ----
    for (int i4 = tid; i4 < (OC * IC * 9) / 4; i4 += 256) {
        const float4 v = ((const float4*)w)[i4];
        const int e0  = i4 * 4;
        const int oc  = e0 / 576;           // 576 % 4 == 0: all 4 elems in same oc row
        const int rem = e0 - oc * 576;
        unsigned* dst = (unsigned*)&lds[oc * WSTRIDE + rem];
        dst[0] = (unsigned)f2bf(v.x) | ((unsigned)f2bf(v.y) << 16);
        dst[1] = (unsigned)f2bf(v.z) | ((unsigned)f2bf(v.w) << 16);
    }
    __syncthreads();

    // ---- Phase 2: gather per-lane A fragments into registers ----
    // global k = s*32 + klocal; klocal = kg*8 + j; k -> (tap = k/64, ic = k%64)
    // A-frag layout (16x16x32): lane holds A[row = lane&15][k = (lane>>4)*8 + j]
    const int oc_a = wv * 16 + l15;
    bf8_t afrag[NS];
    #pragma unroll
    for (int s = 0; s < NS; ++s) {
        const int tap = s >> 1;
        const int ic0 = (s & 1) * 32 + kg * 8;
        #pragma unroll
        for (int j = 0; j < 8; ++j) {
            afrag[s][j] = (short)lds[oc_a * WSTRIDE + (ic0 + j) * 9 + tap];
        }
    }
    __syncthreads();

    // ---- Phase 3: stage x tile (bf16) into LDS: [icb8][r4][col58][ic8] ----
    // One ds_write_b128 per (icb, r, col); global loads are w-contiguous per lane.
    {
        const int col  = lane;          // 0..63, valid < 58
        const int wcol = col - 1;       // input col with pad shift
        const bool cok = (col < LC);
        const bool wok = (wcol >= 0) && (wcol < WW);
        #pragma unroll
        for (int q = 0; q < 8; ++q) {
            const int combo = wv * 8 + q;       // 32 combos = icb(8) x r(4)
            const int icb = combo >> 2;
            const int r   = combo & 3;
            const int h   = h0 - 1 + r;
            const bool ok = cok && wok && (h >= 0) && (h < HH);
            bf8_t v;
            #pragma unroll
            for (int j = 0; j < 8; ++j) {
                float f = 0.f;
                if (ok) f = x[(((b * IC) + icb * 8 + j) * HH + h) * WW + wcol];
                v[j] = (short)f2bf(f);
            }
            if (cok) *(bf8_t*)&lds[((icb * LR + r) * LC + col) * 8] = v;
        }
    }
    __syncthreads();

    // ---- Phase 4: K-loop, 18 steps x 7 pixel tiles, A in regs, B one b128 each ----
    f4_t acc[NT];
    #pragma unroll
    for (int t = 0; t < NT; ++t) acc[t] = 0.f;

    int pixoff[NT], prow[NT], pcol[NT];
    #pragma unroll
    for (int t = 0; t < NT; ++t) {
        const int p  = t * 16 + l15;    // pixel index in block tile
        const int rp = p / WW;
        const int cp = p - rp * WW;
        prow[t] = rp;
        pcol[t] = cp;
        pixoff[t] = (rp * LC + cp) * 16;    // byte offset (pixel part)
    }
    const char* base = (const char*)lds + kg * (LR * LC * 16);  // k-group part

    #pragma unroll
    for (int s = 0; s < NS; ++s) {
        const int tap  = s >> 1;
        const int khh  = tap / 3;
        const int kww  = tap - khh * 3;
        const int soff = (s & 1) * (4 * LR * LC * 16) + (khh * LC + kww) * 16;
        #pragma unroll
        for (int t = 0; t < NT; ++t) {
            bf8_t bv = *(const bf8_t*)(base + soff + pixoff[t]);
            acc[t] = __builtin_amdgcn_mfma_f32_16x16x32_bf16(afrag[s], bv, acc[t], 0, 0, 0);
        }
    }

    // ---- Phase 5: epilogue: bias add + fp32 store ----
    // C/D layout: row(oc_local) = kg*4 + rr, col(pixel) = lane&15
    const int oc_c = wv * 16 + kg * 4;
    const float b0 = bias[oc_c + 0];
    const float b1 = bias[oc_c + 1];
    const float b2 = bias[oc_c + 2];
    const float b3 = bias[oc_c + 3];
    #pragma unroll
    for (int t = 0; t < NT; ++t) {
        const int h = h0 + prow[t];
        const int cp = pcol[t];
        float* o = &out[((b * OC + oc_c) * HH + h) * WW + cp];
        o[0 * HH * WW] = acc[t][0] + b0;
        o[1 * HH * WW] = acc[t][1] + b1;
        o[2 * HH * WW] = acc[t][2] + b2;
        o[3 * HH * WW] = acc[t][3] + b3;
    }
}

extern "C" void kernel_launch(void* const* d_in, const int* in_sizes, int n_in,
                              void* d_out, int out_size, void* d_ws, size_t ws_size,
                              hipStream_t stream) {
    const float* x    = (const float*)d_in[0];
    const float* w    = (const float*)d_in[1];
    const float* bias = (const float*)d_in[2];
    float* out        = (float*)d_out;
    hipLaunchKernelGGL(conv3x3_mfma, dim3(NB * RB), dim3(256), 0, stream,
                       x, w, bias, out);
}